// Round 17
// baseline (7331.864 us; speedup 1.0000x reference)
//
#include <hip/hip_runtime.h>
#include <cstdint>
#include <cstddef>

#define SEQ 4096
#define HID 512
#define NTHETA 5
#define NBLK 4
#define RPB 128                 // rows per block
#define SENT_BITS 0x40000000u   // 2.0f — |tanh| < 1, so never a real h value

typedef unsigned long long u64;

__device__ __forceinline__ float tanh_fast(float x) {
  x = fminf(fmaxf(x, -20.0f), 20.0f);
  const float e = __expf(2.0f * x);
  return (e - 1.0f) / (e + 1.0f);
}

// 16B poll load, agent-visible (sc1 path verified at full speed, r10).
// Wait INSIDE the asm: nothing in flight across exits (r12 lesson).
__device__ __forceinline__ uint4 load_x4_sc1(const unsigned* p) {
  uint4 u;
  asm volatile("global_load_dwordx4 %0, %1, off sc1\n\ts_waitcnt vmcnt(0)"
               : "=v"(u) : "v"(p) : "memory");
  return u;
}

__device__ __forceinline__ bool has_sent(uint4 u) {
  return u.x == SENT_BITS || u.y == SENT_BITS ||
         u.z == SENT_BITS || u.w == SENT_BITS;
}

// Poll a PRIVATE mailbox chunk (1 reader per line at B=4); every 8th spin
// uses scalar agent-atomic loads (r2-proven); after ~4096 spins fall back to
// plane0 (canonical copy, always written) -> guaranteed termination.
__device__ __forceinline__ uint4 poll_chunk(const unsigned* src,
                                            const unsigned* safe) {
  uint4 u = load_x4_sc1(src);
  int it = 0;
  while (has_sent(u)) {
    ++it;
    if ((it & 7) == 0) {
      const unsigned* s = (it >= 4096) ? safe : src;
      u.x = __hip_atomic_load(s + 0, __ATOMIC_RELAXED, __HIP_MEMORY_SCOPE_AGENT);
      u.y = __hip_atomic_load(s + 1, __ATOMIC_RELAXED, __HIP_MEMORY_SCOPE_AGENT);
      u.z = __hip_atomic_load(s + 2, __ATOMIC_RELAXED, __HIP_MEMORY_SCOPE_AGENT);
      u.w = __hip_atomic_load(s + 3, __ATOMIC_RELAXED, __HIP_MEMORY_SCOPE_AGENT);
    } else {
      u = load_x4_sc1(src);
    }
  }
  return u;
}

// Butterfly sum over 16-lane groups: xor1, xor2, xor8 on the VALU (DPP),
// only xor4 on the DS pipe (ds_swizzle). Verified r9/r10.
__device__ __forceinline__ float red16(float v) {
  int p;
  p = __builtin_amdgcn_update_dpp(0, __float_as_int(v), 0xB1, 0xF, 0xF, true);  // ^1
  v += __int_as_float(p);
  p = __builtin_amdgcn_update_dpp(0, __float_as_int(v), 0x4E, 0xF, 0xF, true);  // ^2
  v += __int_as_float(p);
  v += __int_as_float(__builtin_amdgcn_ds_swizzle(__float_as_int(v), 0x101F)); // ^4
  p = __builtin_amdgcn_update_dpp(0, __float_as_int(v), 0x128, 0xF, 0xF, true); // row_ror:8 = ^8
  v += __int_as_float(p);
  return v;
}

// f4-chunk swizzle (<=2-way b128 reads, conflict-free b128 poll writes)
__device__ __forceinline__ int swz(int f) {
  return (f & ~7) | ((f ^ (f >> 3)) & 7);
}

// C[4096,512] = act(A[4096,K] @ W[512,K]^T + bias + noise_plane)
__global__ __launch_bounds__(256) void gemm_bias_noise(
    const float* __restrict__ A, const float* __restrict__ W,
    const float* __restrict__ bias, const float* __restrict__ noise,
    float* __restrict__ C, int K, int doTanh)
{
  const int N = HID;
  const int bm = blockIdx.y, bn = blockIdx.x;
  const int tid = threadIdx.x;
  const int tx = tid & 15, ty = tid >> 4;
  const int row0 = bm * 64, col0 = bn * 64;
  __shared__ float As[16][68];
  __shared__ float Ws[16][68];
  float acc[4][4] = {{0.f, 0.f, 0.f, 0.f}, {0.f, 0.f, 0.f, 0.f},
                     {0.f, 0.f, 0.f, 0.f}, {0.f, 0.f, 0.f, 0.f}};
  const int lrow = tid >> 2, lkq = tid & 3;
  for (int kt = 0; kt < K; kt += 16) {
    const float4 av = *(const float4*)&A[(size_t)(row0 + lrow) * K + kt + lkq * 4];
    const float4 wv = *(const float4*)&W[(size_t)(col0 + lrow) * K + kt + lkq * 4];
    __syncthreads();
    As[lkq * 4 + 0][lrow] = av.x; As[lkq * 4 + 1][lrow] = av.y;
    As[lkq * 4 + 2][lrow] = av.z; As[lkq * 4 + 3][lrow] = av.w;
    Ws[lkq * 4 + 0][lrow] = wv.x; Ws[lkq * 4 + 1][lrow] = wv.y;
    Ws[lkq * 4 + 2][lrow] = wv.z; Ws[lkq * 4 + 3][lrow] = wv.w;
    __syncthreads();
#pragma unroll
    for (int k = 0; k < 16; ++k) {
      const float4 a = *(const float4*)&As[k][ty * 4];
      const float4 bq = *(const float4*)&Ws[k][tx * 4];
      const float a4[4] = {a.x, a.y, a.z, a.w};
      const float b4[4] = {bq.x, bq.y, bq.z, bq.w};
#pragma unroll
      for (int i = 0; i < 4; ++i)
#pragma unroll
        for (int j = 0; j < 4; ++j)
          acc[i][j] = fmaf(a4[i], b4[j], acc[i][j]);
    }
  }
  const float4 bv = *(const float4*)&bias[col0 + tx * 4];
#pragma unroll
  for (int i = 0; i < 4; ++i) {
    const int row = row0 + ty * 4 + i;
    const float4 nv = *(const float4*)&noise[(size_t)row * N + col0 + tx * 4];
    float4 o;
    o.x = acc[i][0] + bv.x + nv.x;
    o.y = acc[i][1] + bv.y + nv.y;
    o.z = acc[i][2] + bv.z + nv.z;
    o.w = acc[i][3] + bv.w + nv.w;
    if (doTanh) {
      o.x = tanh_fast(o.x); o.y = tanh_fast(o.y);
      o.z = tanh_fast(o.z); o.w = tanh_fast(o.w);
    }
    *(float4*)&C[(size_t)row * N + col0 + tx * 4] = o;
  }
}

// Pre-fill planes 0..4 (output/hs + 4 private mailboxes) with sentinel bits.
__global__ void fill_sentinel(uint4* __restrict__ p, int n4) {
  const int i = blockIdx.x * blockDim.x + threadIdx.x;
  if (i < n4) p[i] = make_uint4(SENT_BITS, SENT_BITS, SENT_BITS, SENT_BITS);
}

// Sequential scan h_t = tanh(drive_t + W_hh @ h_{t-1}).
// 4 blocks x 512 thr; block owns 128 rows. Thread (i=tid>>4 -> 0..31,
// j=tid&15) owns rows r0=base+4i..+3, cols 32j..+31 (128 W f32, volatile
// loads -> AGPR-parked, r16-verified perf-safe).
// Exchange: FULLY-PRIVATE mailboxes — consumer block c polls out-plane 1+c
// exclusively => exactly 1 reader per polled line (terminal point of the
// reader-contention axis; r16's <=2-reader version gave -5.5%).
// Per step:
//   - 96 pollers (tid<96) poll one private 16B chunk -> ds_write_b128
//     (swizzled); ONE barrier.
//   - 8 swizzled ds_read_b128 -> 128 FMA (h4 reused across 4 rows)
//     -> 4x red16 (DPP+1 ds_swizzle each).
//   - j==0: 4x tanh, publish rows r0..r0+3 (2 u64 agent stores x
//     {3 remote mailboxes + plane0}), seed own float4 into next LDS buffer.
__global__ __launch_bounds__(512, 2) void recurrence(
    const float* __restrict__ Whh, const float* __restrict__ drive,
    const float* __restrict__ h0, unsigned* __restrict__ plane0,
    unsigned* __restrict__ mail)   // 4 contiguous planes (out planes 1..4)
{
  const size_t PL = (size_t)SEQ * HID;
  const int blk = blockIdx.x;
  const int base = blk * RPB;
  const int tid = threadIdx.x;
  const int i = tid >> 4;        // 0..31
  const int j = tid & 15;        // 0..15
  const int r0 = base + 4 * i;   // first of this thread's four rows

  __shared__ __align__(16) float hbuf[2][HID];

  // W: 4 rows x 32 cols, volatile scalar loads (non-rematerializable)
  float w0[32], w1[32], w2[32], w3[32];
  {
    const volatile float* p0 = &Whh[(size_t)r0 * HID + 32 * j];
#pragma unroll
    for (int c = 0; c < 32; ++c) {
      w0[c] = p0[c];
      w1[c] = p0[c + HID];
      w2[c] = p0[c + 2 * HID];
      w3[c] = p0[c + 3 * HID];
    }
  }

  // poller mapping: tid<96 -> remote f4 chunk (skip own 32 of 128)
  const int ch = (tid < blk * 32) ? tid : tid + 32;   // valid for tid<96
  const int wslot = swz(ch);
  // own-seed slot (j==0): rows r0..r0+3 = full chunk r0>>2 (16B aligned)
  const int z0 = swz(r0 >> 2) * 4;
  // this consumer's fully-private mailbox plane (out plane 1+blk)
  const unsigned* mymail = mail + (size_t)blk * PL;

  // t=0 seed from h0 (512 threads cover 512 floats exactly)
  hbuf[0][swz(tid >> 2) * 4 + (tid & 3)] = h0[tid];

  for (int t = 0; t < SEQ; ++t) {
    const int buf = t & 1;

    float4 dr = make_float4(0.f, 0.f, 0.f, 0.f);
    if (j == 0) dr = *(const float4*)&drive[(size_t)t * HID + r0];

    if (t > 0 && tid < 96) {
      const unsigned* src  = &mymail[(size_t)(t - 1) * HID + 4 * ch];
      const unsigned* safe = &plane0[(size_t)(t - 1) * HID + 4 * ch];
      const uint4 u = poll_chunk(src, safe);
      ((uint4*)hbuf[buf])[wslot] = u;   // one ds_write_b128, swizzled slot
    }
    __syncthreads();   // buf ready; skew <= 1 step => other buffer safe
    asm volatile("" :: "v"(dr.x), "v"(dr.y), "v"(dr.z), "v"(dr.w));

    float a00 = 0.f, a01 = 0.f, a02 = 0.f, a03 = 0.f;
    float a10 = 0.f, a11 = 0.f, a12 = 0.f, a13 = 0.f;
    float a20 = 0.f, a21 = 0.f, a22 = 0.f, a23 = 0.f;
    float a30 = 0.f, a31 = 0.f, a32 = 0.f, a33 = 0.f;
#pragma unroll
    for (int c = 0; c < 8; ++c) {
      const float4 h4 = *(const float4*)&hbuf[buf][(8 * j + ((c ^ j) & 7)) * 4];
      a00 = fmaf(w0[4 * c + 0], h4.x, a00);
      a01 = fmaf(w0[4 * c + 1], h4.y, a01);
      a02 = fmaf(w0[4 * c + 2], h4.z, a02);
      a03 = fmaf(w0[4 * c + 3], h4.w, a03);
      a10 = fmaf(w1[4 * c + 0], h4.x, a10);
      a11 = fmaf(w1[4 * c + 1], h4.y, a11);
      a12 = fmaf(w1[4 * c + 2], h4.z, a12);
      a13 = fmaf(w1[4 * c + 3], h4.w, a13);
      a20 = fmaf(w2[4 * c + 0], h4.x, a20);
      a21 = fmaf(w2[4 * c + 1], h4.y, a21);
      a22 = fmaf(w2[4 * c + 2], h4.z, a22);
      a23 = fmaf(w2[4 * c + 3], h4.w, a23);
      a30 = fmaf(w3[4 * c + 0], h4.x, a30);
      a31 = fmaf(w3[4 * c + 1], h4.y, a31);
      a32 = fmaf(w3[4 * c + 2], h4.z, a32);
      a33 = fmaf(w3[4 * c + 3], h4.w, a33);
    }
    const float s0 = red16((a00 + a01) + (a02 + a03));
    const float s1 = red16((a10 + a11) + (a12 + a13));
    const float s2 = red16((a20 + a21) + (a22 + a23));
    const float s3 = red16((a30 + a31) + (a32 + a33));

    if (j == 0) {
      float4 y;
      y.x = tanh_fast(s0 + dr.x);
      y.y = tanh_fast(s1 + dr.y);
      y.z = tanh_fast(s2 + dr.z);
      y.w = tanh_fast(s3 + dr.w);
      const u64 lo = (u64)__float_as_uint(y.x) | ((u64)__float_as_uint(y.y) << 32);
      const u64 hi = (u64)__float_as_uint(y.z) | ((u64)__float_as_uint(y.w) << 32);
      const size_t off = (size_t)t * HID + r0;
      // 3 remote private mailboxes (latency-critical: 1 reader per line)
#pragma unroll
      for (int c = 0; c < NBLK; ++c) {
        if (c != blk) {
          u64* d = (u64*)&mail[(size_t)c * PL + off];
          __hip_atomic_store(d + 0, lo, __ATOMIC_RELAXED,
                             __HIP_MEMORY_SCOPE_AGENT);
          __hip_atomic_store(d + 1, hi, __ATOMIC_RELAXED,
                             __HIP_MEMORY_SCOPE_AGENT);
        }
      }
      // canonical copy = hs output (also the poll fallback target)
      u64* d0 = (u64*)&plane0[off];
      __hip_atomic_store(d0 + 0, lo, __ATOMIC_RELAXED,
                         __HIP_MEMORY_SCOPE_AGENT);
      __hip_atomic_store(d0 + 1, hi, __ATOMIC_RELAXED,
                         __HIP_MEMORY_SCOPE_AGENT);
      // own rows never leave the CU: seed next LDS buffer (full chunk)
      *(float4*)&hbuf[buf ^ 1][z0] = y;
    }
  }
}

__global__ void copy_final(const float* __restrict__ src, float* __restrict__ dst) {
  dst[threadIdx.x] = src[threadIdx.x];
}

extern "C" void kernel_launch(void* const* d_in, const int* in_sizes, int n_in,
                              void* d_out, int out_size, void* d_ws, size_t ws_size,
                              hipStream_t stream) {
  const float* input    = (const float*)d_in[0];
  const float* internal = (const float*)d_in[1];
  const float* state    = (const float*)d_in[2];
  const float* W_ih     = (const float*)d_in[3];
  const float* W_hh     = (const float*)d_in[4];
  const float* bias     = (const float*)d_in[5];
  float* out = (float*)d_out;

  const size_t plane = (size_t)SEQ * HID;
  // plane 0 = hs output (canonical publish); planes 1..4 = private mailboxes
  // (rewritten by theta GEMMs k=0..3 afterwards); plane 5 = drive
  // (rewritten by theta GEMM k=4 afterwards). All stream-ordered-safe.
  unsigned* plane0 = (unsigned*)out;
  unsigned* mail   = (unsigned*)(out + plane);
  float*    drive  = out + 5 * plane;

  // sentinel planes 0..4
  fill_sentinel<<<((int)(5 * plane / 4) + 255) / 256, 256, 0, stream>>>(
      (uint4*)out, (int)(5 * plane / 4));

  dim3 gg(HID / 64, SEQ / 64);
  // drive = x @ W_ih^T + b + internal[0]   (no tanh)
  gemm_bias_noise<<<gg, 256, 0, stream>>>(input, W_ih, bias, internal, drive,
                                          HID, 0);
  // hs (plane 0) via fully-private mailbox sentinel exchange
  recurrence<<<NBLK, 512, 0, stream>>>(W_hh, drive, state, plane0, mail);
  // theta rollouts: plane k -> plane k+1
  for (int k = 0; k < NTHETA; ++k) {
    gemm_bias_noise<<<gg, 256, 0, stream>>>(out + (size_t)k * plane, W_hh, bias,
                                            internal + (size_t)(k + 1) * plane,
                                            out + (size_t)(k + 1) * plane,
                                            HID, 1);
  }
  // final_state = hs[4095]
  copy_final<<<1, HID, 0, stream>>>(out + (size_t)4095 * HID, out + 6 * plane);
}

// Round 18
// 6141.650 us; speedup vs baseline: 1.1938x; 1.1938x over previous
//
#include <hip/hip_runtime.h>
#include <cstdint>
#include <cstddef>

#define SEQ 4096
#define HID 512
#define NTHETA 5
#define NBLK 8
#define RPB 64                  // rows per block
#define NMAIL 4                 // mailbox planes (out planes 1..4)
#define SENT_BITS 0x40000000u   // 2.0f — |tanh| < 1, so never a real h value

typedef unsigned long long u64;

__device__ __forceinline__ float tanh_fast(float x) {
  x = fminf(fmaxf(x, -20.0f), 20.0f);
  const float e = __expf(2.0f * x);
  return (e - 1.0f) / (e + 1.0f);
}

// 16B poll load, agent-visible (sc1 path verified at full speed, r10).
// Wait INSIDE the asm: nothing in flight across exits (r12 lesson).
__device__ __forceinline__ uint4 load_x4_sc1(const unsigned* p) {
  uint4 u;
  asm volatile("global_load_dwordx4 %0, %1, off sc1\n\ts_waitcnt vmcnt(0)"
               : "=v"(u) : "v"(p) : "memory");
  return u;
}

__device__ __forceinline__ bool has_sent(uint4 u) {
  return u.x == SENT_BITS || u.y == SENT_BITS ||
         u.z == SENT_BITS || u.w == SENT_BITS;
}

// Poll a mailbox chunk (<=2 readers/line at B=8); every 8th spin uses scalar
// agent-atomic loads (r2-proven); after ~4096 spins fall back to plane0
// (canonical copy, always written) -> guaranteed termination.
__device__ __forceinline__ uint4 poll_chunk(const unsigned* src,
                                            const unsigned* safe) {
  uint4 u = load_x4_sc1(src);
  int it = 0;
  while (has_sent(u)) {
    ++it;
    if ((it & 7) == 0) {
      const unsigned* s = (it >= 4096) ? safe : src;
      u.x = __hip_atomic_load(s + 0, __ATOMIC_RELAXED, __HIP_MEMORY_SCOPE_AGENT);
      u.y = __hip_atomic_load(s + 1, __ATOMIC_RELAXED, __HIP_MEMORY_SCOPE_AGENT);
      u.z = __hip_atomic_load(s + 2, __ATOMIC_RELAXED, __HIP_MEMORY_SCOPE_AGENT);
      u.w = __hip_atomic_load(s + 3, __ATOMIC_RELAXED, __HIP_MEMORY_SCOPE_AGENT);
    } else {
      u = load_x4_sc1(src);
    }
  }
  return u;
}

// Butterfly sum over 16-lane groups: xor1, xor2, xor8 on the VALU (DPP),
// only xor4 on the DS pipe (ds_swizzle). Verified r9/r10.
__device__ __forceinline__ float red16(float v) {
  int p;
  p = __builtin_amdgcn_update_dpp(0, __float_as_int(v), 0xB1, 0xF, 0xF, true);  // ^1
  v += __int_as_float(p);
  p = __builtin_amdgcn_update_dpp(0, __float_as_int(v), 0x4E, 0xF, 0xF, true);  // ^2
  v += __int_as_float(p);
  v += __int_as_float(__builtin_amdgcn_ds_swizzle(__float_as_int(v), 0x101F)); // ^4
  p = __builtin_amdgcn_update_dpp(0, __float_as_int(v), 0x128, 0xF, 0xF, true); // row_ror:8 = ^8
  v += __int_as_float(p);
  return v;
}

// f4-chunk swizzle (<=2-way b128 reads, conflict-free b128 poll writes)
__device__ __forceinline__ int swz(int f) {
  return (f & ~7) | ((f ^ (f >> 3)) & 7);
}

// C[4096,512] = act(A[4096,K] @ W[512,K]^T + bias + noise_plane)
__global__ __launch_bounds__(256) void gemm_bias_noise(
    const float* __restrict__ A, const float* __restrict__ W,
    const float* __restrict__ bias, const float* __restrict__ noise,
    float* __restrict__ C, int K, int doTanh)
{
  const int N = HID;
  const int bm = blockIdx.y, bn = blockIdx.x;
  const int tid = threadIdx.x;
  const int tx = tid & 15, ty = tid >> 4;
  const int row0 = bm * 64, col0 = bn * 64;
  __shared__ float As[16][68];
  __shared__ float Ws[16][68];
  float acc[4][4] = {{0.f, 0.f, 0.f, 0.f}, {0.f, 0.f, 0.f, 0.f},
                     {0.f, 0.f, 0.f, 0.f}, {0.f, 0.f, 0.f, 0.f}};
  const int lrow = tid >> 2, lkq = tid & 3;
  for (int kt = 0; kt < K; kt += 16) {
    const float4 av = *(const float4*)&A[(size_t)(row0 + lrow) * K + kt + lkq * 4];
    const float4 wv = *(const float4*)&W[(size_t)(col0 + lrow) * K + kt + lkq * 4];
    __syncthreads();
    As[lkq * 4 + 0][lrow] = av.x; As[lkq * 4 + 1][lrow] = av.y;
    As[lkq * 4 + 2][lrow] = av.z; As[lkq * 4 + 3][lrow] = av.w;
    Ws[lkq * 4 + 0][lrow] = wv.x; Ws[lkq * 4 + 1][lrow] = wv.y;
    Ws[lkq * 4 + 2][lrow] = wv.z; Ws[lkq * 4 + 3][lrow] = wv.w;
    __syncthreads();
#pragma unroll
    for (int k = 0; k < 16; ++k) {
      const float4 a = *(const float4*)&As[k][ty * 4];
      const float4 bq = *(const float4*)&Ws[k][tx * 4];
      const float a4[4] = {a.x, a.y, a.z, a.w};
      const float b4[4] = {bq.x, bq.y, bq.z, bq.w};
#pragma unroll
      for (int i = 0; i < 4; ++i)
#pragma unroll
        for (int j = 0; j < 4; ++j)
          acc[i][j] = fmaf(a4[i], b4[j], acc[i][j]);
    }
  }
  const float4 bv = *(const float4*)&bias[col0 + tx * 4];
#pragma unroll
  for (int i = 0; i < 4; ++i) {
    const int row = row0 + ty * 4 + i;
    const float4 nv = *(const float4*)&noise[(size_t)row * N + col0 + tx * 4];
    float4 o;
    o.x = acc[i][0] + bv.x + nv.x;
    o.y = acc[i][1] + bv.y + nv.y;
    o.z = acc[i][2] + bv.z + nv.z;
    o.w = acc[i][3] + bv.w + nv.w;
    if (doTanh) {
      o.x = tanh_fast(o.x); o.y = tanh_fast(o.y);
      o.z = tanh_fast(o.z); o.w = tanh_fast(o.w);
    }
    *(float4*)&C[(size_t)row * N + col0 + tx * 4] = o;
  }
}

// Pre-fill planes 0..4 (output/hs + 4 mailboxes) with the sentinel bits.
__global__ void fill_sentinel(uint4* __restrict__ p, int n4) {
  const int i = blockIdx.x * blockDim.x + threadIdx.x;
  if (i < n4) p[i] = make_uint4(SENT_BITS, SENT_BITS, SENT_BITS, SENT_BITS);
}

// Sequential scan h_t = tanh(drive_t + W_hh @ h_{t-1}).
// r16 configuration (measured optimum: 5903 us) + s_setprio (T5) around the
// post-barrier compute+publish:
// 8 blocks x 512 thr; block owns 64 rows; thread (i=tid>>4, j=tid&15) owns
// rows r0=base+2i, r0+1, cols 32j..+31 (volatile W loads -> AGPR-parked).
// Mailboxes: consumer pairs {c, c^4} share out-plane 1+(c&3) -> <=2 readers
// per polled line. plane0 = canonical copy = hs output (poll fallback).
// Per step: 112 pollers -> ds_write_b128 swizzled; ONE barrier;
// setprio(1) { 8 swizzled ds_read_b128 -> 64 FMA -> 2x red16; j==0: tanh x2,
// u64 publish to 4 mailboxes + plane0, seed next LDS buffer } setprio(0).
// T5 mechanism: compute/publisher waves preempt the resident pollers' load
// storm -> publish issues earlier -> remote detect earlier.
__global__ __launch_bounds__(512, 2) void recurrence(
    const float* __restrict__ Whh, const float* __restrict__ drive,
    const float* __restrict__ h0, unsigned* __restrict__ plane0,
    unsigned* __restrict__ mail)   // 4 contiguous planes (out planes 1..4)
{
  const size_t PL = (size_t)SEQ * HID;
  const int blk = blockIdx.x;
  const int base = blk * RPB;
  const int tid = threadIdx.x;
  const int i = tid >> 4;        // 0..31
  const int j = tid & 15;        // 0..15
  const int r0 = base + 2 * i;   // first of this thread's two rows

  __shared__ __align__(16) float hbuf[2][HID];

  // W: 2 rows x 32 cols, volatile scalar loads -> non-rematerializable
  float w0[32], w1[32];
  {
    const volatile float* p0 = &Whh[(size_t)r0 * HID + 32 * j];
    const volatile float* p1 = p0 + HID;
#pragma unroll
    for (int c = 0; c < 32; ++c) { w0[c] = p0[c]; w1[c] = p1[c]; }
  }

  // poller mapping: tid<112 -> remote f4 chunk (skip own 16), swizzled slot
  const int ch = (tid < blk * 16) ? tid : tid + 16;   // valid for tid<112
  const int wslot = swz(ch);
  // own-seed slot (j==0): rows r0,r0+1 -> chunk r0>>2, offset r0&3 (0 or 2)
  const int z0 = swz(r0 >> 2) * 4 + (r0 & 3);
  // this consumer's mailbox plane (shared with block blk^4)
  unsigned* mymail = mail + (size_t)(blk & 3) * PL;

  // t=0 seed from h0 (512 threads cover 512 floats exactly)
  hbuf[0][swz(tid >> 2) * 4 + (tid & 3)] = h0[tid];

  for (int t = 0; t < SEQ; ++t) {
    const int buf = t & 1;

    float2 dr = make_float2(0.f, 0.f);
    if (j == 0) dr = *(const float2*)&drive[(size_t)t * HID + r0];

    if (t > 0 && tid < 112) {
      const unsigned* src  = &mymail[(size_t)(t - 1) * HID + 4 * ch];
      const unsigned* safe = &plane0[(size_t)(t - 1) * HID + 4 * ch];
      const uint4 u = poll_chunk(src, safe);
      ((uint4*)hbuf[buf])[wslot] = u;   // one ds_write_b128, swizzled slot
    }
    __syncthreads();   // buf ready; skew <= 1 step => other buffer safe
    asm volatile("" :: "v"(dr.x), "v"(dr.y));   // drv resident by now

    __builtin_amdgcn_s_setprio(1);   // T5: favor compute/publish waves

    float a00 = 0.f, a01 = 0.f, a02 = 0.f, a03 = 0.f;
    float a10 = 0.f, a11 = 0.f, a12 = 0.f, a13 = 0.f;
#pragma unroll
    for (int c = 0; c < 8; ++c) {
      const float4 h4 = *(const float4*)&hbuf[buf][(8 * j + ((c ^ j) & 7)) * 4];
      a00 = fmaf(w0[4 * c + 0], h4.x, a00);
      a01 = fmaf(w0[4 * c + 1], h4.y, a01);
      a02 = fmaf(w0[4 * c + 2], h4.z, a02);
      a03 = fmaf(w0[4 * c + 3], h4.w, a03);
      a10 = fmaf(w1[4 * c + 0], h4.x, a10);
      a11 = fmaf(w1[4 * c + 1], h4.y, a11);
      a12 = fmaf(w1[4 * c + 2], h4.z, a12);
      a13 = fmaf(w1[4 * c + 3], h4.w, a13);
    }
    float s0 = red16((a00 + a01) + (a02 + a03));
    float s1 = red16((a10 + a11) + (a12 + a13));

    if (j == 0) {
      const float y0 = tanh_fast(s0 + dr.x);
      const float y1 = tanh_fast(s1 + dr.y);
      const u64 pk = (u64)__float_as_uint(y0) | ((u64)__float_as_uint(y1) << 32);
      const size_t off = (size_t)t * HID + r0;
      // mailboxes first (latency-critical: each line has <=2 pollers)
#pragma unroll
      for (int m = 0; m < NMAIL; ++m)
        __hip_atomic_store((u64*)&mail[m * PL + off], pk,
                           __ATOMIC_RELAXED, __HIP_MEMORY_SCOPE_AGENT);
      // canonical copy = hs output (also the poll fallback target)
      __hip_atomic_store((u64*)&plane0[off], pk,
                         __ATOMIC_RELAXED, __HIP_MEMORY_SCOPE_AGENT);
      // own rows never leave the CU: seed next LDS buffer directly.
      *(float2*)&hbuf[buf ^ 1][z0] = make_float2(y0, y1);
    }

    __builtin_amdgcn_s_setprio(0);   // pollers spin at low priority
  }
}

__global__ void copy_final(const float* __restrict__ src, float* __restrict__ dst) {
  dst[threadIdx.x] = src[threadIdx.x];
}

extern "C" void kernel_launch(void* const* d_in, const int* in_sizes, int n_in,
                              void* d_out, int out_size, void* d_ws, size_t ws_size,
                              hipStream_t stream) {
  const float* input    = (const float*)d_in[0];
  const float* internal = (const float*)d_in[1];
  const float* state    = (const float*)d_in[2];
  const float* W_ih     = (const float*)d_in[3];
  const float* W_hh     = (const float*)d_in[4];
  const float* bias     = (const float*)d_in[5];
  float* out = (float*)d_out;

  const size_t plane = (size_t)SEQ * HID;
  // plane 0 = hs output (canonical publish); planes 1..4 = mailboxes
  // (rewritten by theta GEMMs k=0..3 afterwards); plane 5 = drive
  // (rewritten by theta GEMM k=4 afterwards). All stream-ordered-safe.
  unsigned* plane0 = (unsigned*)out;
  unsigned* mail   = (unsigned*)(out + plane);
  float*    drive  = out + 5 * plane;

  // sentinel planes 0..4
  fill_sentinel<<<((int)(5 * plane / 4) + 255) / 256, 256, 0, stream>>>(
      (uint4*)out, (int)(5 * plane / 4));

  dim3 gg(HID / 64, SEQ / 64);
  // drive = x @ W_ih^T + b + internal[0]   (no tanh)
  gemm_bias_noise<<<gg, 256, 0, stream>>>(input, W_ih, bias, internal, drive,
                                          HID, 0);
  // hs (plane 0) via mailbox sentinel exchange
  recurrence<<<NBLK, 512, 0, stream>>>(W_hh, drive, state, plane0, mail);
  // theta rollouts: plane k -> plane k+1
  for (int k = 0; k < NTHETA; ++k) {
    gemm_bias_noise<<<gg, 256, 0, stream>>>(out + (size_t)k * plane, W_hh, bias,
                                            internal + (size_t)(k + 1) * plane,
                                            out + (size_t)(k + 1) * plane,
                                            HID, 1);
  }
  // final_state = hs[4095]
  copy_final<<<1, HID, 0, stream>>>(out + (size_t)4095 * HID, out + 6 * plane);
}

// Round 19
// 6110.946 us; speedup vs baseline: 1.1998x; 1.0050x over previous
//
#include <hip/hip_runtime.h>
#include <cstdint>
#include <cstddef>

#define SEQ 4096
#define HID 512
#define NTHETA 5
#define NBLK 8
#define RPB 64                  // rows per block
#define NMAIL 4                 // mailbox planes (out planes 1..4)
#define SENT_BITS 0x40000000u   // 2.0f — |tanh| < 1, so never a real h value

typedef unsigned long long u64;

__device__ __forceinline__ float tanh_fast(float x) {
  x = fminf(fmaxf(x, -20.0f), 20.0f);
  const float e = __expf(2.0f * x);
  return (e - 1.0f) / (e + 1.0f);
}

// 16B poll load, agent-visible (sc1 path verified at full speed, r10).
// Wait INSIDE the asm: nothing in flight across exits (r12 lesson).
__device__ __forceinline__ uint4 load_x4_sc1(const unsigned* p) {
  uint4 u;
  asm volatile("global_load_dwordx4 %0, %1, off sc1\n\ts_waitcnt vmcnt(0)"
               : "=v"(u) : "v"(p) : "memory");
  return u;
}

__device__ __forceinline__ bool has_sent(uint4 u) {
  return u.x == SENT_BITS || u.y == SENT_BITS ||
         u.z == SENT_BITS || u.w == SENT_BITS;
}

// Poll a mailbox chunk (<=2 readers/line at B=8); every 8th spin uses scalar
// agent-atomic loads (r2-proven); after ~4096 spins fall back to plane0
// (canonical copy, always written) -> guaranteed termination.
__device__ __forceinline__ uint4 poll_chunk(const unsigned* src,
                                            const unsigned* safe) {
  uint4 u = load_x4_sc1(src);
  int it = 0;
  while (has_sent(u)) {
    ++it;
    if ((it & 7) == 0) {
      const unsigned* s = (it >= 4096) ? safe : src;
      u.x = __hip_atomic_load(s + 0, __ATOMIC_RELAXED, __HIP_MEMORY_SCOPE_AGENT);
      u.y = __hip_atomic_load(s + 1, __ATOMIC_RELAXED, __HIP_MEMORY_SCOPE_AGENT);
      u.z = __hip_atomic_load(s + 2, __ATOMIC_RELAXED, __HIP_MEMORY_SCOPE_AGENT);
      u.w = __hip_atomic_load(s + 3, __ATOMIC_RELAXED, __HIP_MEMORY_SCOPE_AGENT);
    } else {
      u = load_x4_sc1(src);
    }
  }
  return u;
}

// Butterfly sum over 16-lane groups: xor1, xor2, xor8 on the VALU (DPP),
// only xor4 on the DS pipe (ds_swizzle). Verified r9/r10.
__device__ __forceinline__ float red16(float v) {
  int p;
  p = __builtin_amdgcn_update_dpp(0, __float_as_int(v), 0xB1, 0xF, 0xF, true);  // ^1
  v += __int_as_float(p);
  p = __builtin_amdgcn_update_dpp(0, __float_as_int(v), 0x4E, 0xF, 0xF, true);  // ^2
  v += __int_as_float(p);
  v += __int_as_float(__builtin_amdgcn_ds_swizzle(__float_as_int(v), 0x101F)); // ^4
  p = __builtin_amdgcn_update_dpp(0, __float_as_int(v), 0x128, 0xF, 0xF, true); // row_ror:8 = ^8
  v += __int_as_float(p);
  return v;
}

// f4-chunk swizzle (<=2-way b128 reads, conflict-free b128 poll writes)
__device__ __forceinline__ int swz(int f) {
  return (f & ~7) | ((f ^ (f >> 3)) & 7);
}

// C[4096,512] = act(A[4096,512] @ W[512,512]^T + bias + noise_plane)
// 128x64 tile, 512 thr, 4x4 acc/thread, double-buffered LDS, global
// prefetch->regs hidden under compute, ONE barrier per K-step.
// (Round-19 upgrade: old 64x64/2-barrier GEMM measured ~43 TF = 27% of the
// 157 TF f32 vector peak; this targets ~55-65%.)
__global__ __launch_bounds__(512) void gemm_fast(
    const float* __restrict__ A, const float* __restrict__ W,
    const float* __restrict__ bias, const float* __restrict__ noise,
    float* __restrict__ C, int doTanh)
{
  const int K = HID, N = HID;
  const int bn = blockIdx.x, bm = blockIdx.y;
  const int row0 = bm * 128, col0 = bn * 64;
  const int tid = threadIdx.x;
  const int tx = tid & 15, ty = tid >> 4;       // cols 4*tx.., rows 4*ty..
  const int aRow = tid >> 2, aK = (tid & 3) * 4; // A staging: f4 along K
  const int wCol = tid >> 3, wK = (tid & 7) * 2; // W staging: f2 along K

  __shared__ __align__(16) float As[2][16][132];  // [k][row], +4 pad
  __shared__ __align__(16) float Ws[2][16][68];   // [k][col], +4 pad

  float acc[4][4] = {{0.f,0.f,0.f,0.f},{0.f,0.f,0.f,0.f},
                     {0.f,0.f,0.f,0.f},{0.f,0.f,0.f,0.f}};

  // prologue: tile 0 -> LDS[0]
  {
    const float4 av = *(const float4*)&A[(size_t)(row0 + aRow) * K + aK];
    const float2 wv = *(const float2*)&W[(size_t)(col0 + wCol) * K + wK];
    As[0][aK + 0][aRow] = av.x; As[0][aK + 1][aRow] = av.y;
    As[0][aK + 2][aRow] = av.z; As[0][aK + 3][aRow] = av.w;
    Ws[0][wK + 0][wCol] = wv.x; Ws[0][wK + 1][wCol] = wv.y;
  }
  __syncthreads();

  for (int kt = 0; kt < 32; ++kt) {
    const int buf = kt & 1;
    float4 aN; float2 wN;
    if (kt < 31) {   // issue next-tile global loads; latency hides under FMAs
      const int k0 = (kt + 1) * 16;
      aN = *(const float4*)&A[(size_t)(row0 + aRow) * K + k0 + aK];
      wN = *(const float2*)&W[(size_t)(col0 + wCol) * K + k0 + wK];
    }
#pragma unroll
    for (int k = 0; k < 16; ++k) {
      const float4 a4 = *(const float4*)&As[buf][k][4 * ty];
      const float4 w4 = *(const float4*)&Ws[buf][k][4 * tx];
      const float ar[4] = {a4.x, a4.y, a4.z, a4.w};
      const float wr[4] = {w4.x, w4.y, w4.z, w4.w};
#pragma unroll
      for (int r = 0; r < 4; ++r)
#pragma unroll
        for (int c = 0; c < 4; ++c)
          acc[r][c] = fmaf(ar[r], wr[c], acc[r][c]);
    }
    if (kt < 31) {   // store prefetched tile into the other buffer
      As[buf ^ 1][aK + 0][aRow] = aN.x; As[buf ^ 1][aK + 1][aRow] = aN.y;
      As[buf ^ 1][aK + 2][aRow] = aN.z; As[buf ^ 1][aK + 3][aRow] = aN.w;
      Ws[buf ^ 1][wK + 0][wCol] = wN.x; Ws[buf ^ 1][wK + 1][wCol] = wN.y;
    }
    __syncthreads();  // readers done with buf AND writers done with buf^1
  }

  const float4 bv = *(const float4*)&bias[col0 + 4 * tx];
#pragma unroll
  for (int r = 0; r < 4; ++r) {
    const int row = row0 + 4 * ty + r;
    const float4 nv = *(const float4*)&noise[(size_t)row * N + col0 + 4 * tx];
    float4 o;
    o.x = acc[r][0] + bv.x + nv.x;
    o.y = acc[r][1] + bv.y + nv.y;
    o.z = acc[r][2] + bv.z + nv.z;
    o.w = acc[r][3] + bv.w + nv.w;
    if (doTanh) {
      o.x = tanh_fast(o.x); o.y = tanh_fast(o.y);
      o.z = tanh_fast(o.z); o.w = tanh_fast(o.w);
    }
    *(float4*)&C[(size_t)row * N + col0 + 4 * tx] = o;
  }
}

// Pre-fill planes 0..4 (output/hs + 4 mailboxes) with the sentinel bits.
__global__ void fill_sentinel(uint4* __restrict__ p, int n4) {
  const int i = blockIdx.x * blockDim.x + threadIdx.x;
  if (i < n4) p[i] = make_uint4(SENT_BITS, SENT_BITS, SENT_BITS, SENT_BITS);
}

// Sequential scan h_t = tanh(drive_t + W_hh @ h_{t-1}).
// r18 configuration FROZEN (measured best: 5823 us): 8 blocks x 512 thr,
// 2 rows/thread (volatile W -> AGPR-parked), <=2-reader mailboxes,
// sc1-x4 sentinel poll + agent backstop + plane0 fallback, swizzled LDS
// double-buffer, ONE barrier, DPP reduce, setprio(1) around compute+publish.
__global__ __launch_bounds__(512, 2) void recurrence(
    const float* __restrict__ Whh, const float* __restrict__ drive,
    const float* __restrict__ h0, unsigned* __restrict__ plane0,
    unsigned* __restrict__ mail)   // 4 contiguous planes (out planes 1..4)
{
  const size_t PL = (size_t)SEQ * HID;
  const int blk = blockIdx.x;
  const int base = blk * RPB;
  const int tid = threadIdx.x;
  const int i = tid >> 4;        // 0..31
  const int j = tid & 15;        // 0..15
  const int r0 = base + 2 * i;   // first of this thread's two rows

  __shared__ __align__(16) float hbuf[2][HID];

  // W: 2 rows x 32 cols, volatile scalar loads -> non-rematerializable
  float w0[32], w1[32];
  {
    const volatile float* p0 = &Whh[(size_t)r0 * HID + 32 * j];
    const volatile float* p1 = p0 + HID;
#pragma unroll
    for (int c = 0; c < 32; ++c) { w0[c] = p0[c]; w1[c] = p1[c]; }
  }

  // poller mapping: tid<112 -> remote f4 chunk (skip own 16), swizzled slot
  const int ch = (tid < blk * 16) ? tid : tid + 16;   // valid for tid<112
  const int wslot = swz(ch);
  // own-seed slot (j==0): rows r0,r0+1 -> chunk r0>>2, offset r0&3 (0 or 2)
  const int z0 = swz(r0 >> 2) * 4 + (r0 & 3);
  // this consumer's mailbox plane (shared with block blk^4)
  unsigned* mymail = mail + (size_t)(blk & 3) * PL;

  // t=0 seed from h0 (512 threads cover 512 floats exactly)
  hbuf[0][swz(tid >> 2) * 4 + (tid & 3)] = h0[tid];

  for (int t = 0; t < SEQ; ++t) {
    const int buf = t & 1;

    float2 dr = make_float2(0.f, 0.f);
    if (j == 0) dr = *(const float2*)&drive[(size_t)t * HID + r0];

    if (t > 0 && tid < 112) {
      const unsigned* src  = &mymail[(size_t)(t - 1) * HID + 4 * ch];
      const unsigned* safe = &plane0[(size_t)(t - 1) * HID + 4 * ch];
      const uint4 u = poll_chunk(src, safe);
      ((uint4*)hbuf[buf])[wslot] = u;   // one ds_write_b128, swizzled slot
    }
    __syncthreads();   // buf ready; skew <= 1 step => other buffer safe
    asm volatile("" :: "v"(dr.x), "v"(dr.y));   // drv resident by now

    __builtin_amdgcn_s_setprio(1);   // T5: favor compute/publish waves

    float a00 = 0.f, a01 = 0.f, a02 = 0.f, a03 = 0.f;
    float a10 = 0.f, a11 = 0.f, a12 = 0.f, a13 = 0.f;
#pragma unroll
    for (int c = 0; c < 8; ++c) {
      const float4 h4 = *(const float4*)&hbuf[buf][(8 * j + ((c ^ j) & 7)) * 4];
      a00 = fmaf(w0[4 * c + 0], h4.x, a00);
      a01 = fmaf(w0[4 * c + 1], h4.y, a01);
      a02 = fmaf(w0[4 * c + 2], h4.z, a02);
      a03 = fmaf(w0[4 * c + 3], h4.w, a03);
      a10 = fmaf(w1[4 * c + 0], h4.x, a10);
      a11 = fmaf(w1[4 * c + 1], h4.y, a11);
      a12 = fmaf(w1[4 * c + 2], h4.z, a12);
      a13 = fmaf(w1[4 * c + 3], h4.w, a13);
    }
    float s0 = red16((a00 + a01) + (a02 + a03));
    float s1 = red16((a10 + a11) + (a12 + a13));

    if (j == 0) {
      const float y0 = tanh_fast(s0 + dr.x);
      const float y1 = tanh_fast(s1 + dr.y);
      const u64 pk = (u64)__float_as_uint(y0) | ((u64)__float_as_uint(y1) << 32);
      const size_t off = (size_t)t * HID + r0;
      // mailboxes first (latency-critical: each line has <=2 pollers)
#pragma unroll
      for (int m = 0; m < NMAIL; ++m)
        __hip_atomic_store((u64*)&mail[m * PL + off], pk,
                           __ATOMIC_RELAXED, __HIP_MEMORY_SCOPE_AGENT);
      // canonical copy = hs output (also the poll fallback target)
      __hip_atomic_store((u64*)&plane0[off], pk,
                         __ATOMIC_RELAXED, __HIP_MEMORY_SCOPE_AGENT);
      // own rows never leave the CU: seed next LDS buffer directly.
      *(float2*)&hbuf[buf ^ 1][z0] = make_float2(y0, y1);
    }

    __builtin_amdgcn_s_setprio(0);   // pollers spin at low priority
  }
}

__global__ void copy_final(const float* __restrict__ src, float* __restrict__ dst) {
  dst[threadIdx.x] = src[threadIdx.x];
}

extern "C" void kernel_launch(void* const* d_in, const int* in_sizes, int n_in,
                              void* d_out, int out_size, void* d_ws, size_t ws_size,
                              hipStream_t stream) {
  const float* input    = (const float*)d_in[0];
  const float* internal = (const float*)d_in[1];
  const float* state    = (const float*)d_in[2];
  const float* W_ih     = (const float*)d_in[3];
  const float* W_hh     = (const float*)d_in[4];
  const float* bias     = (const float*)d_in[5];
  float* out = (float*)d_out;

  const size_t plane = (size_t)SEQ * HID;
  // plane 0 = hs output (canonical publish); planes 1..4 = mailboxes
  // (rewritten by theta GEMMs k=0..3 afterwards); plane 5 = drive
  // (rewritten by theta GEMM k=4 afterwards). All stream-ordered-safe.
  unsigned* plane0 = (unsigned*)out;
  unsigned* mail   = (unsigned*)(out + plane);
  float*    drive  = out + 5 * plane;

  // sentinel planes 0..4
  fill_sentinel<<<((int)(5 * plane / 4) + 255) / 256, 256, 0, stream>>>(
      (uint4*)out, (int)(5 * plane / 4));

  dim3 gg(HID / 64, SEQ / 128);   // 8 x 32 = 256 blocks, 1/CU
  // drive = x @ W_ih^T + b + internal[0]   (no tanh)
  gemm_fast<<<gg, 512, 0, stream>>>(input, W_ih, bias, internal, drive, 0);
  // hs (plane 0) via mailbox sentinel exchange
  recurrence<<<NBLK, 512, 0, stream>>>(W_hh, drive, state, plane0, mail);
  // theta rollouts: plane k -> plane k+1
  for (int k = 0; k < NTHETA; ++k) {
    gemm_fast<<<gg, 512, 0, stream>>>(out + (size_t)k * plane, W_hh, bias,
                                      internal + (size_t)(k + 1) * plane,
                                      out + (size_t)(k + 1) * plane, 1);
  }
  // final_state = hs[4095]
  copy_final<<<1, HID, 0, stream>>>(out + (size_t)4095 * HID, out + 6 * plane);
}